// Round 3
// baseline (713.345 us; speedup 1.0000x reference)
//
#include <hip/hip_runtime.h>

typedef _Float16 f16;
typedef _Float16 f16x8 __attribute__((ext_vector_type(8)));
typedef float f32x4 __attribute__((ext_vector_type(4)));

#define NROWS 131072
#define DIMS  64
#define KC    1024
#define BETA  0.25f

// output offsets (floats)
#define OFF_Q      0
#define OFF_LOSS   8388608
#define OFF_EMB    8388609
#define OFF_COUNT  (8388609 + 65536)
#define OFF_EMBSUM (8388609 + 65536 + 1024)

// ws layout (floats)
#define WS_LOSS   0
#define WS_COUNTS 64
#define WS_SUMS   (64 + 1024)                 // [K][D]
#define WS_NORME  (64 + 1024 + 65536)
#define WS_TOTAL  (64 + 1024 + 65536 + 1024)

// Prep: transpose emb [D][K] -> f16 hi/lo [K][D] (stashed in d_out's EMBSUM
// region, overwritten later by vq_final), plus normE[k] = sum_d e^2 in fp32.
__global__ void vq_prep(const float* __restrict__ emb, float* __restrict__ ws,
                        f16* __restrict__ ehT, f16* __restrict__ elT) {
    __shared__ float buf[64][65];
    const int t = threadIdx.x;
    const int k0 = blockIdx.x * 64;
    #pragma unroll
    for (int it = 0; it < 16; ++it) {
        int idx = it * 256 + t;
        int kk = idx & 63, d = idx >> 6;
        buf[kk][d] = emb[(size_t)d * KC + k0 + kk];   // coalesced over kk
    }
    __syncthreads();
    if (t < 64) {
        float s = 0.f;
        #pragma unroll 8
        for (int d = 0; d < 64; ++d) { float v = buf[t][d]; s += v * v; }
        ws[WS_NORME + k0 + t] = s;
    }
    #pragma unroll
    for (int it = 0; it < 16; ++it) {
        int idx = it * 256 + t;
        int d = idx & 63, kk = idx >> 6;
        float v = buf[kk][d];
        f16 hi = (f16)v;
        f16 lo = (f16)(v - (float)hi);
        ehT[(size_t)(k0 + kk) * 64 + d] = hi;         // coalesced over d
        elT[(size_t)(k0 + kk) * 64 + d] = lo;
    }
}

__launch_bounds__(256)
__global__ void vq_main(const float* __restrict__ x, const f16* __restrict__ ehT,
                        const f16* __restrict__ elT, float* __restrict__ q_out,
                        float* __restrict__ ws) {
    // eh/el (GEMM phase) and xT (epilogue phase) share the same LDS.
    __shared__ union SMem {
        struct { f16 eh[128 * 64]; f16 el[128 * 64]; } g;   // XOR-swizzled [code][d]
        float xT[128][65];                                   // padded x tile
    } smem;
    __shared__ int best_k[128];

    const int t    = threadIdx.x;
    const int lane = t & 63;
    const int wv   = t >> 6;         // 4 waves, 32 rows each
    const int brow = blockIdx.x * 128;
    const int l15  = lane & 15;
    const int l4   = lane >> 4;

    // A fragments: rows of x converted to f16 hi/lo in registers.
    // mfma_f32_16x16x32_f16 A layout: row = lane&15, k = (lane>>4)*8 + j
    f16x8 ahi[2][2], alo[2][2];
    #pragma unroll
    for (int rt = 0; rt < 2; ++rt) {
        int row = brow + wv * 32 + rt * 16 + l15;
        #pragma unroll
        for (int ks = 0; ks < 2; ++ks) {
            int d0 = ks * 32 + l4 * 8;
            const float* p = x + (size_t)row * 64 + d0;
            float4 v0 = *(const float4*)p;
            float4 v1 = *(const float4*)(p + 4);
            float vv[8] = {v0.x, v0.y, v0.z, v0.w, v1.x, v1.y, v1.z, v1.w};
            f16x8 h, l;
            #pragma unroll
            for (int j = 0; j < 8; ++j) {
                f16 hj = (f16)vv[j];
                h[j] = hj;
                l[j] = (f16)(vv[j] - (float)hj);
            }
            ahi[rt][ks] = h; alo[rt][ks] = l;
        }
    }

    float bdist[2][4];
    int   bidx[2][4];
    #pragma unroll
    for (int rt = 0; rt < 2; ++rt)
        #pragma unroll
        for (int r = 0; r < 4; ++r) { bdist[rt][r] = 1e30f; bidx[rt][r] = 0; }

    const char* ehTb = (const char*)ehT;
    const char* elTb = (const char*)elT;
    char* ehb = (char*)smem.g.eh;
    char* elb = (char*)smem.g.el;

    for (int kc0 = 0; kc0 < KC; kc0 += 128) {
        __syncthreads();
        // stage 128 codes x 64 dims, hi+lo (16KB each); XOR-swizzle dest so
        // B-frag ds_read_b128 (row stride 128B) is bank-conflict-free.
        #pragma unroll
        for (int it = 0; it < 4; ++it) {
            int n = (it * 256 + t) * 16;          // byte offset within chunk
            int code  = n >> 7;
            int inner = n & 127;
            int dswz  = (code << 7) | (inner ^ ((code & 7) << 4));
            float4 vh = *(const float4*)(ehTb + (size_t)kc0 * 128 + n);
            float4 vl = *(const float4*)(elTb + (size_t)kc0 * 128 + n);
            *(float4*)(ehb + dswz) = vh;
            *(float4*)(elb + dswz) = vl;
        }
        __syncthreads();

        #pragma unroll
        for (int ct = 0; ct < 8; ++ct) {
            int code = ct * 16 + l15;             // B col = lane&15
            f16x8 bh[2], bl[2];
            #pragma unroll
            for (int ks = 0; ks < 2; ++ks) {
                int inner = ks * 64 + l4 * 16;    // k = (lane>>4)*8 + j
                int off = (code << 7) | (inner ^ ((code & 7) << 4));
                bh[ks] = *(const f16x8*)(ehb + off);
                bl[ks] = *(const f16x8*)(elb + off);
            }
            int gcol = kc0 + code;
            float nE = ws[WS_NORME + gcol];
            #pragma unroll
            for (int rt = 0; rt < 2; ++rt) {
                f32x4 acc = {0.f, 0.f, 0.f, 0.f};
                #pragma unroll
                for (int ks = 0; ks < 2; ++ks) {
                    acc = __builtin_amdgcn_mfma_f32_16x16x32_f16(ahi[rt][ks], bh[ks], acc, 0, 0, 0);
                    acc = __builtin_amdgcn_mfma_f32_16x16x32_f16(alo[rt][ks], bh[ks], acc, 0, 0, 0);
                    acc = __builtin_amdgcn_mfma_f32_16x16x32_f16(ahi[rt][ks], bl[ks], acc, 0, 0, 0);
                }
                // C/D layout: col = lane&15, row = (lane>>4)*4 + reg
                #pragma unroll
                for (int r = 0; r < 4; ++r) {
                    float dist = nE - 2.f * acc[r];
                    if (dist < bdist[rt][r]) { bdist[rt][r] = dist; bidx[rt][r] = gcol; }
                }
            }
        }
    }

    // reduce argmin across the 16 lanes holding the same row (vary lane&15)
    #pragma unroll
    for (int rt = 0; rt < 2; ++rt) {
        #pragma unroll
        for (int r = 0; r < 4; ++r) {
            float d = bdist[rt][r]; int k = bidx[rt][r];
            #pragma unroll
            for (int m = 1; m <= 8; m <<= 1) {
                float d2 = __shfl_xor(d, m, 64);
                int   k2 = __shfl_xor(k, m, 64);
                if (d2 < d || (d2 == d && k2 < k)) { d = d2; k = k2; }
            }
            if (l15 == 0) {
                int rloc = wv * 32 + rt * 16 + l4 * 4 + r;
                best_k[rloc] = k;
                atomicAdd(&ws[WS_COUNTS + k], 1.0f);
            }
        }
    }
    __syncthreads();   // best_k ready; all eh/el readers done -> xT may alias

    // Pass 1 (coalesced): quantized gather, loss, and stage x tile into LDS.
    float lsum = 0.f;
    #pragma unroll 4
    for (int it = 0; it < 32; ++it) {
        int r = it * 4 + wv;
        int d = lane;
        int k = best_k[r];                        // wave-uniform broadcast
        float q = (float)ehT[(size_t)k * 64 + d] + (float)elT[(size_t)k * 64 + d];
        size_t gi = (size_t)(brow + r) * 64 + d;
        float xv = x[gi];
        float diff = q - xv;
        lsum += diff * diff;
        q_out[gi] = q;
        smem.xT[r][d] = xv;
    }
    #pragma unroll
    for (int o = 32; o > 0; o >>= 1) lsum += __shfl_down(lsum, o);
    if (lane == 0) atomicAdd(&ws[WS_LOSS], lsum);
    __syncthreads();

    // Pass 2 (transposed scatter): lane carries a ROW -> 64 lanes hit ~64
    // distinct code rows -> atomic bursts spread across L2 channels instead
    // of serializing on one 256B chunk.
    {
        int r = (wv & 1) * 64 + lane;
        int k = best_k[r];
        int d0 = (wv >> 1) * 32;
        #pragma unroll 8
        for (int j = 0; j < 32; ++j) {
            int d = d0 + j;
            atomicAdd(&ws[WS_SUMS + k * 64 + d], smem.xT[r][d]);
        }
    }
}

__global__ void vq_final(const float* __restrict__ sample_count,
                         const float* __restrict__ embeddings_sum,
                         const float* __restrict__ ws, float* __restrict__ out) {
    int i = blockIdx.x * blockDim.x + threadIdx.x;   // over D*K
    int d = i >> 10;
    int k = i & 1023;
    float cnt = sample_count[k] + ws[WS_COUNTS + k];
    float ns  = embeddings_sum[i] + ws[WS_SUMS + k * DIMS + d];
    out[OFF_EMBSUM + i] = ns;
    out[OFF_EMB + i]    = ns / fmaxf(cnt, 1e-5f);
    if (i < KC) out[OFF_COUNT + i] = sample_count[i] + ws[WS_COUNTS + i];
    if (i == 0) out[OFF_LOSS] = BETA * ws[WS_LOSS] * (1.0f / ((float)NROWS * (float)DIMS));
}

extern "C" void kernel_launch(void* const* d_in, const int* in_sizes, int n_in,
                              void* d_out, int out_size, void* d_ws, size_t ws_size,
                              hipStream_t stream) {
    const float* x      = (const float*)d_in[0];
    const float* emb    = (const float*)d_in[1];
    const float* scount = (const float*)d_in[2];
    const float* esum   = (const float*)d_in[3];
    float* out = (float*)d_out;
    float* ws  = (float*)d_ws;

    // f16 hi/lo transposed codebook lives in the EMBSUM output region until
    // vq_final overwrites it (131072B + 131072B == 65536 floats exactly).
    f16* ehT = (f16*)(out + OFF_EMBSUM);
    f16* elT = ehT + KC * DIMS;

    hipMemsetAsync(d_ws, 0, WS_TOTAL * sizeof(float), stream);
    vq_prep<<<KC / 64, 256, 0, stream>>>(emb, ws, ehT, elT);
    vq_main<<<NROWS / 128, 256, 0, stream>>>(x, ehT, elT, out, ws);
    vq_final<<<(DIMS * KC) / 256, 256, 0, stream>>>(scount, esum, ws, out);
}

// Round 4
// 185.665 us; speedup vs baseline: 3.8421x; 3.8421x over previous
//
#include <hip/hip_runtime.h>

typedef _Float16 f16;
typedef _Float16 f16x8 __attribute__((ext_vector_type(8)));
typedef float f32x4 __attribute__((ext_vector_type(4)));

#define NROWS 131072
#define DIMS  64
#define KC    1024
#define BETA  0.25f

// output offsets (floats)
#define OFF_Q      0
#define OFF_LOSS   8388608
#define OFF_EMB    8388609
#define OFF_COUNT  (8388609 + 65536)
#define OFF_EMBSUM (8388609 + 65536 + 1024)

// ws layout
#define WS_NORME  0                       // float[1024]
#define WS_ET     1024                    // float eT[K][D] (exact fp32 transpose)
#define WS_IDX    (1024 + 65536)          // int[N] best-code per row

// Prep: transpose emb [D][K] -> fp32 eT[K][D] (ws) + f16 hi/lo [K][D]
// (stashed in d_out's EMBSUM region, overwritten later by vq_scatter),
// plus normE[k] = sum_d e^2.
__global__ void vq_prep(const float* __restrict__ emb, float* __restrict__ ws,
                        f16* __restrict__ ehT, f16* __restrict__ elT) {
    __shared__ float buf[64][65];
    const int t = threadIdx.x;
    const int k0 = blockIdx.x * 64;
    #pragma unroll
    for (int it = 0; it < 16; ++it) {
        int idx = it * 256 + t;
        int kk = idx & 63, d = idx >> 6;
        buf[kk][d] = emb[(size_t)d * KC + k0 + kk];   // coalesced over kk
    }
    __syncthreads();
    if (t < 64) {
        float s = 0.f;
        #pragma unroll 8
        for (int d = 0; d < 64; ++d) { float v = buf[t][d]; s += v * v; }
        ws[WS_NORME + k0 + t] = s;
    }
    #pragma unroll
    for (int it = 0; it < 16; ++it) {
        int idx = it * 256 + t;
        int d = idx & 63, kk = idx >> 6;
        float v = buf[kk][d];
        f16 hi = (f16)v;
        f16 lo = (f16)(v - (float)hi);
        ws[WS_ET + (size_t)(k0 + kk) * 64 + d] = v;   // coalesced over d
        ehT[(size_t)(k0 + kk) * 64 + d] = hi;
        elT[(size_t)(k0 + kk) * 64 + d] = lo;
    }
}

__launch_bounds__(256)
__global__ void vq_main(const float* __restrict__ x, const f16* __restrict__ ehT,
                        const f16* __restrict__ elT, float* __restrict__ q_out,
                        float* __restrict__ ws) {
    __shared__ f16 eh[128 * 64];     // XOR-swizzled [code][d]
    __shared__ f16 el[128 * 64];
    __shared__ int best_k[128];

    const int t    = threadIdx.x;
    const int lane = t & 63;
    const int wv   = t >> 6;         // 4 waves, 32 rows each
    const int brow = blockIdx.x * 128;
    const int l15  = lane & 15;
    const int l4   = lane >> 4;

    // A fragments: rows of x converted to f16 hi/lo in registers.
    // mfma_f32_16x16x32_f16 A layout: row = lane&15, k = (lane>>4)*8 + j
    f16x8 ahi[2][2], alo[2][2];
    #pragma unroll
    for (int rt = 0; rt < 2; ++rt) {
        int row = brow + wv * 32 + rt * 16 + l15;
        #pragma unroll
        for (int ks = 0; ks < 2; ++ks) {
            int d0 = ks * 32 + l4 * 8;
            const float* p = x + (size_t)row * 64 + d0;
            float4 v0 = *(const float4*)p;
            float4 v1 = *(const float4*)(p + 4);
            float vv[8] = {v0.x, v0.y, v0.z, v0.w, v1.x, v1.y, v1.z, v1.w};
            f16x8 h, l;
            #pragma unroll
            for (int j = 0; j < 8; ++j) {
                f16 hj = (f16)vv[j];
                h[j] = hj;
                l[j] = (f16)(vv[j] - (float)hj);
            }
            ahi[rt][ks] = h; alo[rt][ks] = l;
        }
    }

    float bdist[2][4];
    int   bidx[2][4];
    #pragma unroll
    for (int rt = 0; rt < 2; ++rt)
        #pragma unroll
        for (int r = 0; r < 4; ++r) { bdist[rt][r] = 1e30f; bidx[rt][r] = 0; }

    const char* ehTb = (const char*)ehT;
    const char* elTb = (const char*)elT;
    char* ehb = (char*)eh;
    char* elb = (char*)el;

    for (int kc0 = 0; kc0 < KC; kc0 += 128) {
        __syncthreads();
        // stage 128 codes x 64 dims, hi+lo (16KB each); XOR-swizzle dest so
        // B-frag ds_read_b128 (row stride 128B) is bank-conflict-free.
        #pragma unroll
        for (int it = 0; it < 4; ++it) {
            int n = (it * 256 + t) * 16;          // byte offset within chunk
            int code  = n >> 7;
            int inner = n & 127;
            int dswz  = (code << 7) | (inner ^ ((code & 7) << 4));
            float4 vh = *(const float4*)(ehTb + (size_t)kc0 * 128 + n);
            float4 vl = *(const float4*)(elTb + (size_t)kc0 * 128 + n);
            *(float4*)(ehb + dswz) = vh;
            *(float4*)(elb + dswz) = vl;
        }
        __syncthreads();

        #pragma unroll
        for (int ct = 0; ct < 8; ++ct) {
            int code = ct * 16 + l15;             // B col = lane&15
            f16x8 bh[2], bl[2];
            #pragma unroll
            for (int ks = 0; ks < 2; ++ks) {
                int inner = ks * 64 + l4 * 16;    // k = (lane>>4)*8 + j
                int off = (code << 7) | (inner ^ ((code & 7) << 4));
                bh[ks] = *(const f16x8*)(ehb + off);
                bl[ks] = *(const f16x8*)(elb + off);
            }
            int gcol = kc0 + code;
            float nE = ws[WS_NORME + gcol];
            #pragma unroll
            for (int rt = 0; rt < 2; ++rt) {
                f32x4 acc = {0.f, 0.f, 0.f, 0.f};
                #pragma unroll
                for (int ks = 0; ks < 2; ++ks) {
                    acc = __builtin_amdgcn_mfma_f32_16x16x32_f16(ahi[rt][ks], bh[ks], acc, 0, 0, 0);
                    acc = __builtin_amdgcn_mfma_f32_16x16x32_f16(alo[rt][ks], bh[ks], acc, 0, 0, 0);
                    acc = __builtin_amdgcn_mfma_f32_16x16x32_f16(ahi[rt][ks], bl[ks], acc, 0, 0, 0);
                }
                // C/D layout: col = lane&15, row = (lane>>4)*4 + reg
                #pragma unroll
                for (int r = 0; r < 4; ++r) {
                    float dist = nE - 2.f * acc[r];
                    if (dist < bdist[rt][r]) { bdist[rt][r] = dist; bidx[rt][r] = gcol; }
                }
            }
        }
    }

    // reduce argmin across the 16 lanes holding the same row (vary lane&15)
    #pragma unroll
    for (int rt = 0; rt < 2; ++rt) {
        #pragma unroll
        for (int r = 0; r < 4; ++r) {
            float d = bdist[rt][r]; int k = bidx[rt][r];
            #pragma unroll
            for (int m = 1; m <= 8; m <<= 1) {
                float d2 = __shfl_xor(d, m, 64);
                int   k2 = __shfl_xor(k, m, 64);
                if (d2 < d || (d2 == d && k2 < k)) { d = d2; k = k2; }
            }
            if (l15 == 0) {
                int rloc = wv * 32 + rt * 16 + l4 * 4 + r;
                best_k[rloc] = k;
            }
        }
    }
    __syncthreads();

    // epilogue: write idx + coalesced q gather from exact fp32 eT. No atomics.
    int* idxout = (int*)(ws + WS_IDX);
    if (t < 128) idxout[brow + t] = best_k[t];
    const float* eT = ws + WS_ET;
    #pragma unroll 4
    for (int it = 0; it < 32; ++it) {
        int r = it * 4 + wv;
        int k = best_k[r];                        // wave-uniform broadcast
        q_out[(size_t)(brow + r) * 64 + lane] = eT[(size_t)k * 64 + lane];
    }
}

// One block per code k: scan idx[] (L2-resident), gather matching x rows.
// Produces counts (exact int), sums, loss, and all codebook outputs directly.
__launch_bounds__(256)
__global__ void vq_scatter(const float* __restrict__ x, const float* __restrict__ ws,
                           const float* __restrict__ scount,
                           const float* __restrict__ esum,
                           float* __restrict__ out) {
    __shared__ float ssum[4][64];
    __shared__ float slsum[4];
    __shared__ int   scnt[4];

    const int k    = blockIdx.x;
    const int t    = threadIdx.x;
    const int lane = t & 63;
    const int wv   = t >> 6;

    const float ek = ws[WS_ET + (size_t)k * 64 + lane];
    const int4* idx4 = (const int4*)(ws + WS_IDX);

    float sum = 0.f, lsum = 0.f;
    int cnt = 0;

    // wave wv scans int4 elements [wv*8192, (wv+1)*8192) -> 32768 rows
    const int base = wv * (NROWS / 16);
    for (int i0 = 0; i0 < NROWS / 16; i0 += 64) {
        int4 v = idx4[base + i0 + lane];
        #pragma unroll
        for (int j = 0; j < 4; ++j) {
            int vj = (j == 0) ? v.x : (j == 1) ? v.y : (j == 2) ? v.z : v.w;
            unsigned long long m = __ballot(vj == k);
            cnt += (int)__popcll(m);
            while (m) {
                int b = __builtin_ctzll(m);
                m &= m - 1;
                int row = (base + i0 + b) * 4 + j;
                float xv = x[(size_t)row * 64 + lane];   // coalesced 256B
                sum += xv;
                float diff = xv - ek;
                lsum += diff * diff;
            }
        }
    }

    // loss: reduce across lanes (dims) within wave
    #pragma unroll
    for (int o = 32; o > 0; o >>= 1) lsum += __shfl_down(lsum, o);
    ssum[wv][lane] = sum;
    if (lane == 0) { scnt[wv] = cnt; slsum[wv] = lsum; }
    __syncthreads();

    if (wv == 0) {
        float s = ssum[0][lane] + ssum[1][lane] + ssum[2][lane] + ssum[3][lane];
        int   c = scnt[0] + scnt[1] + scnt[2] + scnt[3];
        float cf = scount[k] + (float)c;
        float ns = esum[(size_t)lane * KC + k] + s;
        out[OFF_EMBSUM + (size_t)lane * KC + k] = ns;
        out[OFF_EMB    + (size_t)lane * KC + k] = ns / fmaxf(cf, 1e-5f);
        if (lane == 0) {
            out[OFF_COUNT + k] = cf;
            float lp = slsum[0] + slsum[1] + slsum[2] + slsum[3];
            atomicAdd(&out[OFF_LOSS], lp * (BETA / ((float)NROWS * (float)DIMS)));
        }
    }
}

extern "C" void kernel_launch(void* const* d_in, const int* in_sizes, int n_in,
                              void* d_out, int out_size, void* d_ws, size_t ws_size,
                              hipStream_t stream) {
    const float* x      = (const float*)d_in[0];
    const float* emb    = (const float*)d_in[1];
    const float* scount = (const float*)d_in[2];
    const float* esum   = (const float*)d_in[3];
    float* out = (float*)d_out;
    float* ws  = (float*)d_ws;

    // f16 hi/lo transposed codebook lives in the EMBSUM output region until
    // vq_scatter overwrites it (131072B + 131072B == 65536 floats exactly).
    f16* ehT = (f16*)(out + OFF_EMBSUM);
    f16* elT = ehT + KC * DIMS;

    hipMemsetAsync(out + OFF_LOSS, 0, sizeof(float), stream);
    vq_prep<<<KC / 64, 256, 0, stream>>>(emb, ws, ehT, elT);
    vq_main<<<NROWS / 128, 256, 0, stream>>>(x, ehT, elT, out, ws);
    vq_scatter<<<KC, 256, 0, stream>>>(x, ws, scount, esum, out);
}

// Round 5
// 165.731 us; speedup vs baseline: 4.3042x; 1.1203x over previous
//
#include <hip/hip_runtime.h>

typedef _Float16 f16;
typedef _Float16 f16x8 __attribute__((ext_vector_type(8)));
typedef float f32x4 __attribute__((ext_vector_type(4)));

#define NROWS 131072
#define DIMS  64
#define KC    1024
#define BETA  0.25f

// output offsets (floats)
#define OFF_Q      0
#define OFF_LOSS   8388608
#define OFF_EMB    8388609
#define OFF_COUNT  (8388609 + 65536)
#define OFF_EMBSUM (8388609 + 65536 + 1024)

// ws dword offsets (16-dword aligned) — binned path, needs 1.52 MB
#define WS_NORME  0
#define WS_ET     1024
#define WS_EHT    66560        // f16[65536] = 32768 dwords
#define WS_ELT    99328        // f16[65536]
#define WS_IDX    132096       // int[131072]
#define WS_HIST   263168       // int[1024]
#define WS_OFF    264192       // int[1025] (padded)
#define WS_CUR    265232       // int[1024]
#define WS_RID    266256       // int[131072]
#define WS_TOTAL_DW 397328

// fallback (R4) layout
#define WS_IDX_FB (1024 + 65536)

__global__ void vq_prep(const float* __restrict__ emb, float* __restrict__ ws,
                        f16* __restrict__ ehT, f16* __restrict__ elT) {
    __shared__ float buf[64][65];
    const int t = threadIdx.x;
    const int k0 = blockIdx.x * 64;
    #pragma unroll
    for (int it = 0; it < 16; ++it) {
        int idx = it * 256 + t;
        int kk = idx & 63, d = idx >> 6;
        buf[kk][d] = emb[(size_t)d * KC + k0 + kk];   // coalesced over kk
    }
    __syncthreads();
    if (t < 64) {
        float s = 0.f;
        #pragma unroll 8
        for (int d = 0; d < 64; ++d) { float v = buf[t][d]; s += v * v; }
        ws[WS_NORME + k0 + t] = s;
    }
    #pragma unroll
    for (int it = 0; it < 16; ++it) {
        int idx = it * 256 + t;
        int d = idx & 63, kk = idx >> 6;
        float v = buf[kk][d];
        f16 hi = (f16)v;
        f16 lo = (f16)(v - (float)hi);
        ws[WS_ET + (size_t)(k0 + kk) * 64 + d] = v;   // coalesced over d
        ehT[(size_t)(k0 + kk) * 64 + d] = hi;
        elT[(size_t)(k0 + kk) * 64 + d] = lo;
    }
}

template <bool DMA>
__launch_bounds__(256, 4)
__global__ void vq_main_t(const float* __restrict__ x, const f16* __restrict__ ehT,
                          const f16* __restrict__ elT, const float* __restrict__ ws,
                          float* __restrict__ q_out, int* __restrict__ idxout,
                          int* __restrict__ hist) {
    __shared__ f16 eh[128 * 64];     // XOR-swizzled [code][d]
    __shared__ f16 el[128 * 64];
    __shared__ float nEl[1024];
    __shared__ int best_k[128];

    const int t    = threadIdx.x;
    const int lane = t & 63;
    const int wv   = t >> 6;         // 4 waves, 32 rows each
    const int brow = blockIdx.x * 128;
    const int l15  = lane & 15;
    const int l4   = lane >> 4;

    // preload normE (read via MFMA C-operand init below)
    #pragma unroll
    for (int j = 0; j < 4; ++j) nEl[t + j * 256] = ws[WS_NORME + t + j * 256];

    // A fragments: rows of x as f16 hi/lo. A layout: row=lane&15, k=(lane>>4)*8+j
    f16x8 ahi[2][2], alo[2][2];
    #pragma unroll
    for (int rt = 0; rt < 2; ++rt) {
        int row = brow + wv * 32 + rt * 16 + l15;
        #pragma unroll
        for (int ks = 0; ks < 2; ++ks) {
            int d0 = ks * 32 + l4 * 8;
            const float* p = x + (size_t)row * 64 + d0;
            float4 v0 = *(const float4*)p;
            float4 v1 = *(const float4*)(p + 4);
            float vv[8] = {v0.x, v0.y, v0.z, v0.w, v1.x, v1.y, v1.z, v1.w};
            f16x8 h, l;
            #pragma unroll
            for (int j = 0; j < 8; ++j) {
                f16 hj = (f16)vv[j];
                h[j] = hj;
                l[j] = (f16)(vv[j] - (float)hj);
            }
            ahi[rt][ks] = h; alo[rt][ks] = l;
        }
    }

    // per-thread pre-swizzled staging source offsets (both-sides rule:
    // inverse-swizzled global source + linear LDS dest; read applies same XOR)
    int swz[4];
    #pragma unroll
    for (int it = 0; it < 4; ++it) {
        int n = (it * 256 + t) * 16;
        int code = n >> 7, inner = n & 127;
        swz[it] = (code << 7) | (inner ^ ((code & 7) << 4));
    }

    float bmax[2][4];
    int   bidx[2][4];
    #pragma unroll
    for (int rt = 0; rt < 2; ++rt)
        #pragma unroll
        for (int r = 0; r < 4; ++r) { bmax[rt][r] = -1e30f; bidx[rt][r] = 0; }

    for (int kc0 = 0; kc0 < KC; kc0 += 128) {
        __syncthreads();
        if constexpr (DMA) {
            #pragma unroll
            for (int it = 0; it < 4; ++it) {
                int lo = (it * 256 + wv * 64) * 16;   // wave-uniform base, lane*16 auto
                const char* gh = (const char*)ehT + (size_t)kc0 * 128 + swz[it];
                const char* gl = (const char*)elT + (size_t)kc0 * 128 + swz[it];
                __builtin_amdgcn_global_load_lds(
                    (const __attribute__((address_space(1))) void*)gh,
                    (__attribute__((address_space(3))) void*)((char*)eh + lo), 16, 0, 0);
                __builtin_amdgcn_global_load_lds(
                    (const __attribute__((address_space(1))) void*)gl,
                    (__attribute__((address_space(3))) void*)((char*)el + lo), 16, 0, 0);
            }
        } else {
            #pragma unroll
            for (int it = 0; it < 4; ++it) {
                int n = (it * 256 + t) * 16;
                float4 vh = *(const float4*)((const char*)ehT + (size_t)kc0 * 128 + n);
                float4 vl = *(const float4*)((const char*)elT + (size_t)kc0 * 128 + n);
                *(float4*)((char*)eh + swz[it]) = vh;
                *(float4*)((char*)el + swz[it]) = vl;
            }
        }
        __syncthreads();

        #pragma unroll
        for (int ct = 0; ct < 8; ++ct) {
            int code = ct * 16 + l15;             // B col = lane&15
            f16x8 bh[2], bl[2];
            #pragma unroll
            for (int ks = 0; ks < 2; ++ks) {
                int inner = ks * 64 + l4 * 16;    // k = (lane>>4)*8 + j
                int off = (code << 7) | (inner ^ ((code & 7) << 4));
                bh[ks] = *(const f16x8*)((char*)eh + off);
                bl[ks] = *(const f16x8*)((char*)el + off);
            }
            int gcol = kc0 + code;
            float c0 = -0.5f * nEl[gcol];         // dist = -2*(sim - nE/2): track max acc
            #pragma unroll
            for (int rt = 0; rt < 2; ++rt) {
                f32x4 acc = {c0, c0, c0, c0};
                #pragma unroll
                for (int ks = 0; ks < 2; ++ks) {
                    acc = __builtin_amdgcn_mfma_f32_16x16x32_f16(ahi[rt][ks], bh[ks], acc, 0, 0, 0);
                    acc = __builtin_amdgcn_mfma_f32_16x16x32_f16(alo[rt][ks], bh[ks], acc, 0, 0, 0);
                    acc = __builtin_amdgcn_mfma_f32_16x16x32_f16(ahi[rt][ks], bl[ks], acc, 0, 0, 0);
                }
                // C/D layout: col = lane&15, row = (lane>>4)*4 + reg
                #pragma unroll
                for (int r = 0; r < 4; ++r) {
                    if (acc[r] > bmax[rt][r]) { bmax[rt][r] = acc[r]; bidx[rt][r] = gcol; }
                }
            }
        }
    }

    // argmax reduce across the 16 lanes holding the same row (tie -> lower k)
    #pragma unroll
    for (int rt = 0; rt < 2; ++rt) {
        #pragma unroll
        for (int r = 0; r < 4; ++r) {
            float a = bmax[rt][r]; int k = bidx[rt][r];
            #pragma unroll
            for (int m = 1; m <= 8; m <<= 1) {
                float a2 = __shfl_xor(a, m, 64);
                int   k2 = __shfl_xor(k, m, 64);
                if (a2 > a || (a2 == a && k2 < k)) { a = a2; k = k2; }
            }
            if (l15 == 0) {
                int rloc = wv * 32 + rt * 16 + l4 * 4 + r;
                best_k[rloc] = k;
                if (hist) atomicAdd(&hist[k], 1);
            }
        }
    }
    __syncthreads();

    // epilogue: idx + coalesced q gather from exact fp32 eT. No sum atomics.
    if (t < 128) idxout[brow + t] = best_k[t];
    const float* eT = ws + WS_ET;
    #pragma unroll 4
    for (int it = 0; it < 32; ++it) {
        int r = it * 4 + wv;
        int k = best_k[r];                        // wave-uniform broadcast
        q_out[(size_t)(brow + r) * 64 + lane] = eT[(size_t)k * 64 + lane];
    }
}

// 1 block, 1024 threads: prefix-scan hist -> offsets + cursors; count output.
__global__ void vq_scan(const float* __restrict__ scount, int* __restrict__ wsI,
                        float* __restrict__ out) {
    __shared__ int sh[1024];
    const int t = threadIdx.x;
    int* hist = wsI + WS_HIST;
    int* off  = wsI + WS_OFF;
    int* cur  = wsI + WS_CUR;
    int h = hist[t];
    sh[t] = h;
    for (int o = 1; o < 1024; o <<= 1) {
        __syncthreads();
        int u = (t >= o) ? sh[t - o] : 0;
        __syncthreads();
        sh[t] += u;
    }
    __syncthreads();
    int exc = sh[t] - h;
    off[t] = exc;
    cur[t] = exc;
    if (t == 1023) off[1024] = sh[t];
    out[OFF_COUNT + t] = scount[t] + (float)h;
}

// bin rows by code: 131072 same-line cursor atomics + rowid writes.
__global__ void vq_bin(int* __restrict__ wsI) {
    const int i = blockIdx.x * blockDim.x + threadIdx.x;
    int k = wsI[WS_IDX + i];
    int pos = atomicAdd(&wsI[WS_CUR + k], 1);
    wsI[WS_RID + pos] = i;
}

// one block per code: sum its rows (each x row read exactly once, coalesced).
__launch_bounds__(256)
__global__ void vq_sum(const float* __restrict__ x, const float* __restrict__ ws,
                       const float* __restrict__ scount, const float* __restrict__ esum,
                       float* __restrict__ out) {
    __shared__ float ssum[4][64];
    __shared__ float sl[4];
    const int k    = blockIdx.x;
    const int t    = threadIdx.x;
    const int lane = t & 63;
    const int wv   = t >> 6;
    const int* wsI = (const int*)ws;
    const int* rid = wsI + WS_RID;
    const int o0 = wsI[WS_OFF + k];
    const int o1 = wsI[WS_OFF + k + 1];
    const float ek = ws[WS_ET + (size_t)k * 64 + lane];

    float sA = 0.f, sB = 0.f, lA = 0.f, lB = 0.f;
    int i = o0 + wv;
    for (; i + 4 < o1; i += 8) {
        int rA = rid[i], rB = rid[i + 4];
        float xA = x[(size_t)rA * 64 + lane];
        float xB = x[(size_t)rB * 64 + lane];
        sA += xA; float dA = xA - ek; lA += dA * dA;
        sB += xB; float dB = xB - ek; lB += dB * dB;
    }
    if (i < o1) {
        int rA = rid[i];
        float xA = x[(size_t)rA * 64 + lane];
        sA += xA; float dA = xA - ek; lA += dA * dA;
    }
    float sum = sA + sB, ls = lA + lB;
    #pragma unroll
    for (int o = 32; o > 0; o >>= 1) ls += __shfl_down(ls, o);
    ssum[wv][lane] = sum;
    if (lane == 0) sl[wv] = ls;
    __syncthreads();
    if (wv == 0) {
        float s = ssum[0][lane] + ssum[1][lane] + ssum[2][lane] + ssum[3][lane];
        float cf = out[OFF_COUNT + k];            // scount + hist, already written
        float ns = esum[(size_t)lane * KC + k] + s;
        out[OFF_EMBSUM + (size_t)lane * KC + k] = ns;
        out[OFF_EMB    + (size_t)lane * KC + k] = ns / fmaxf(cf, 1e-5f);
        if (lane == 0) {
            float lp = sl[0] + sl[1] + sl[2] + sl[3];
            atomicAdd(&out[OFF_LOSS], lp * (BETA / ((float)NROWS * (float)DIMS)));
        }
    }
}

// fallback (R4): scan-based cluster update, one block per code.
__launch_bounds__(256)
__global__ void vq_scatter(const float* __restrict__ x, const float* __restrict__ ws,
                           const int* __restrict__ idx, const float* __restrict__ scount,
                           const float* __restrict__ esum, float* __restrict__ out) {
    __shared__ float ssum[4][64];
    __shared__ float slsum[4];
    __shared__ int   scnt[4];
    const int k    = blockIdx.x;
    const int t    = threadIdx.x;
    const int lane = t & 63;
    const int wv   = t >> 6;
    const float ek = ws[WS_ET + (size_t)k * 64 + lane];
    const int4* idx4 = (const int4*)idx;
    float sum = 0.f, lsum = 0.f;
    int cnt = 0;
    const int base = wv * (NROWS / 16);
    for (int i0 = 0; i0 < NROWS / 16; i0 += 64) {
        int4 v = idx4[base + i0 + lane];
        #pragma unroll
        for (int j = 0; j < 4; ++j) {
            int vj = (j == 0) ? v.x : (j == 1) ? v.y : (j == 2) ? v.z : v.w;
            unsigned long long m = __ballot(vj == k);
            cnt += (int)__popcll(m);
            while (m) {
                int b = __builtin_ctzll(m);
                m &= m - 1;
                int row = (base + i0 + b) * 4 + j;
                float xv = x[(size_t)row * 64 + lane];
                sum += xv;
                float diff = xv - ek;
                lsum += diff * diff;
            }
        }
    }
    #pragma unroll
    for (int o = 32; o > 0; o >>= 1) lsum += __shfl_down(lsum, o);
    ssum[wv][lane] = sum;
    if (lane == 0) { scnt[wv] = cnt; slsum[wv] = lsum; }
    __syncthreads();
    if (wv == 0) {
        float s = ssum[0][lane] + ssum[1][lane] + ssum[2][lane] + ssum[3][lane];
        int   c = scnt[0] + scnt[1] + scnt[2] + scnt[3];
        float cf = scount[k] + (float)c;
        float ns = esum[(size_t)lane * KC + k] + s;
        out[OFF_EMBSUM + (size_t)lane * KC + k] = ns;
        out[OFF_EMB    + (size_t)lane * KC + k] = ns / fmaxf(cf, 1e-5f);
        if (lane == 0) {
            out[OFF_COUNT + k] = cf;
            float lp = slsum[0] + slsum[1] + slsum[2] + slsum[3];
            atomicAdd(&out[OFF_LOSS], lp * (BETA / ((float)NROWS * (float)DIMS)));
        }
    }
}

extern "C" void kernel_launch(void* const* d_in, const int* in_sizes, int n_in,
                              void* d_out, int out_size, void* d_ws, size_t ws_size,
                              hipStream_t stream) {
    const float* x      = (const float*)d_in[0];
    const float* emb    = (const float*)d_in[1];
    const float* scount = (const float*)d_in[2];
    const float* esum   = (const float*)d_in[3];
    float* out = (float*)d_out;
    float* ws  = (float*)d_ws;

    const bool binned = ws_size >= (size_t)WS_TOTAL_DW * 4;
    f16 *ehT, *elT;
    int *idx, *hist;
    if (binned) {
        ehT = (f16*)(ws + WS_EHT); elT = (f16*)(ws + WS_ELT);
        idx = (int*)ws + WS_IDX;   hist = (int*)ws + WS_HIST;
    } else {
        ehT = (f16*)(out + OFF_EMBSUM); elT = ehT + KC * DIMS;
        idx = (int*)ws + WS_IDX_FB;     hist = nullptr;
    }

    hipMemsetAsync(out + OFF_LOSS, 0, 4, stream);
    vq_prep<<<KC / 64, 256, 0, stream>>>(emb, ws, ehT, elT);
    if (binned) {
        hipMemsetAsync((int*)ws + WS_HIST, 0, 1024 * 4, stream);
        vq_main_t<true><<<NROWS / 128, 256, 0, stream>>>(x, ehT, elT, ws, out, idx, hist);
        vq_scan<<<1, 1024, 0, stream>>>(scount, (int*)ws, out);
        vq_bin<<<NROWS / 256, 256, 0, stream>>>((int*)ws);
        vq_sum<<<KC, 256, 0, stream>>>(x, ws, scount, esum, out);
    } else {
        vq_main_t<false><<<NROWS / 128, 256, 0, stream>>>(x, ehT, elT, ws, out, idx, hist);
        vq_scatter<<<KC, 256, 0, stream>>>(x, ws, idx, scount, esum, out);
    }
}